// Round 5
// baseline (177.092 us; speedup 1.0000x reference)
//
#include <hip/hip_runtime.h>
#include <hip/hip_bf16.h>

typedef __bf16 bf16x8 __attribute__((ext_vector_type(8)));
typedef float f32x16 __attribute__((ext_vector_type(16)));

#define AS1 __attribute__((address_space(1)))
#define AS3 __attribute__((address_space(3)))

static __device__ __forceinline__ void gld_lds16(const float* g, float* l) {
    __builtin_amdgcn_global_load_lds((const AS1 void*)g, (AS3 void*)l, 16, 0, 0);
}

// ---- role: Gram of [nrows x 64] (optional gather) via bf16 MFMA -------------
// WAVE-SYNCHRONOUS: each wave stages exactly the 16 rows (of each 64-row tile)
// that it alone consumes -> no barriers in the K-loop. Triple-buffered LDS,
// counted vmcnt(8/4/0). 3 MFMAs per tile -> G00,G01,G11 32x32 tiles.
template<bool GATHER>
static __device__ __forceinline__ void gram_role(
    const float* __restrict__ emb, const int* __restrict__ idx,
    int nrows, int ntiles, int nblocks, int bid,
    float* __restrict__ partial, float (*lds)[64][64], int t) {
    const int wave = t >> 6, lane = t & 63;
    const int kh = lane >> 5, c = lane & 31;

    // wave w stages rows [w*16, w*16+16) of the tile: 4 calls x 4 rows.
    auto stage = [&](int tile, int buf) {
#pragma unroll
        for (int r = 0; r < 4; ++r) {
            int rg = tile * 64 + wave * 16 + r * 4 + (lane >> 4);
            if (rg >= nrows) rg = nrows - 1;           // clamp; zeroed at compute
            const size_t row = GATHER ? (size_t)idx[rg] : (size_t)rg;
            const float* src = emb + row * 64 + (lane & 15) * 4;
            float* dst = &lds[buf][wave * 16 + r * 4][0];   // wave-uniform base
            gld_lds16(src, dst);
        }
    };

    f32x16 g00 = {}, g01 = {}, g11 = {};
    if (bid < ntiles) stage(bid, 0);
    if (bid + nblocks < ntiles) stage(bid + nblocks, 1);
    if (bid + 2 * nblocks < ntiles) stage(bid + 2 * nblocks, 2);
    int buf = 0;
    for (int tile = bid; tile < ntiles; tile += nblocks, buf = (buf == 2 ? 0 : buf + 1)) {
        if (GATHER) {
            asm volatile("s_waitcnt vmcnt(0)" ::: "memory");
        } else if (tile + 2 * nblocks < ntiles) {
            asm volatile("s_waitcnt vmcnt(8)" ::: "memory");
        } else if (tile + nblocks < ntiles) {
            asm volatile("s_waitcnt vmcnt(4)" ::: "memory");
        } else {
            asm volatile("s_waitcnt vmcnt(0)" ::: "memory");
        }
        const int kb = wave * 16 + kh * 8;
        bf16x8 f0, f1;
        if (tile * 64 + 64 <= nrows) {
#pragma unroll
            for (int j = 0; j < 8; ++j) {
                f0[j] = (__bf16)lds[buf][kb + j][c];
                f1[j] = (__bf16)lds[buf][kb + j][c + 32];
            }
        } else {
#pragma unroll
            for (int j = 0; j < 8; ++j) {
                const bool ok = (tile * 64 + kb + j) < nrows;
                f0[j] = (__bf16)(ok ? lds[buf][kb + j][c] : 0.0f);
                f1[j] = (__bf16)(ok ? lds[buf][kb + j][c + 32] : 0.0f);
            }
        }
        g00 = __builtin_amdgcn_mfma_f32_32x32x16_bf16(f0, f0, g00, 0, 0, 0);
        g01 = __builtin_amdgcn_mfma_f32_32x32x16_bf16(f0, f1, g01, 0, 0, 0);
        g11 = __builtin_amdgcn_mfma_f32_32x32x16_bf16(f1, f1, g11, 0, 0, 0);
        if (tile + 3 * nblocks < ntiles) stage(tile + 3 * nblocks, buf);
    }
    asm volatile("s_waitcnt vmcnt(0)" ::: "memory");   // drain before LDS reuse

    // combine 4 waves in LDS, write one plain partial per block (no atomics)
    __syncthreads();
    float* red = &lds[0][0][0];
    for (int w = 0; w < 4; ++w) {
        if (wave == w) {
#pragma unroll
            for (int r = 0; r < 16; ++r) {
                const int cell = ((r & 3) + 8 * (r >> 2) + 4 * kh) * 32 + c;
                if (w == 0) {
                    red[cell] = g00[r]; red[1024 + cell] = g01[r]; red[2048 + cell] = g11[r];
                } else {
                    red[cell] += g00[r]; red[1024 + cell] += g01[r]; red[2048 + cell] += g11[r];
                }
            }
        }
        __syncthreads();
    }
    float* outp = partial + (size_t)bid * 3072;
    for (int i = t; i < 3072; i += 256) outp[i] = red[i];
}

// ---- role: pos_score sums. Each thread owns one history item of the current
// user; u*h broadcast via LDS (bank-broadcast reads are free).
static __device__ __forceinline__ void pos_role(
    const int* __restrict__ users, const int* __restrict__ hist,
    const float* __restrict__ user_emb, const float* __restrict__ item_emb,
    const float* __restrict__ Hw, int batch, int histL, int pid, int NP,
    float* __restrict__ p1, float* __restrict__ p2, float (*lds)[64][64], int t) {
    float4* uh4 = reinterpret_cast<float4*>(&lds[0][0][0]);
    float s1 = 0.f, s2 = 0.f;
    for (int b = pid; b < batch; b += NP) {
        const int iu = users[b];
        __syncthreads();
        if (t < 16) {
            const float4 vu = *reinterpret_cast<const float4*>(user_emb + (size_t)iu * 64 + t * 4);
            const float4 vh = *reinterpret_cast<const float4*>(Hw + t * 4);
            uh4[t] = make_float4(vu.x * vh.x, vu.y * vh.y, vu.z * vh.z, vu.w * vh.w);
        }
        __syncthreads();
        if (t < histL) {
            const int it = hist[(size_t)iu * histL + t];
            const float* ip = item_emb + (size_t)it * 64;
            float d = 0.f;
#pragma unroll
            for (int half = 0; half < 2; ++half) {
                float4 v[8];
#pragma unroll
                for (int k = 0; k < 8; ++k)
                    v[k] = reinterpret_cast<const float4*>(ip)[half * 8 + k];
#pragma unroll
                for (int k = 0; k < 8; ++k) {
                    const float4 u = uh4[half * 8 + k];
                    d = fmaf(v[k].x, u.x, d); d = fmaf(v[k].y, u.y, d);
                    d = fmaf(v[k].z, u.z, d); d = fmaf(v[k].w, u.w, d);
                }
            }
            s1 += d;
            s2 = fmaf(d, d, s2);
        }
    }
#pragma unroll
    for (int off = 32; off >= 1; off >>= 1) {
        s1 += __shfl_xor(s1, off, 64);
        s2 += __shfl_xor(s2, off, 64);
    }
    __syncthreads();
    float* r = &lds[0][0][0];
    if ((t & 63) == 0) { r[t >> 6] = s1; r[4 + (t >> 6)] = s2; }
    __syncthreads();
    if (t == 0) {
        p1[pid] = r[0] + r[1] + r[2] + r[3];
        p2[pid] = r[4] + r[5] + r[6] + r[7];
    }
}

// ---- role: sum of squares of a flat f32 buffer -----------------------------
static __device__ __forceinline__ void sumsq_role(
    const float* __restrict__ x, int n4, int cid, int NC,
    float* __restrict__ pss, float (*lds)[64][64], int t) {
    float s = 0.f;
    for (int i = cid * 256 + t; i < n4; i += NC * 256) {
        const float4 v = reinterpret_cast<const float4*>(x)[i];
        s = fmaf(v.x, v.x, s); s = fmaf(v.y, v.y, s);
        s = fmaf(v.z, v.z, s); s = fmaf(v.w, v.w, s);
    }
#pragma unroll
    for (int off = 32; off >= 1; off >>= 1) s += __shfl_xor(s, off, 64);
    float* r = &lds[0][0][0];
    if ((t & 63) == 0) r[t >> 6] = s;
    __syncthreads();
    if (t == 0) pss[cid] = r[0] + r[1] + r[2] + r[3];
}

// ---- fused heavy kernel: block-role partition so the independent memory
// streams (item gram / pos gather / user sumsq / user gram) share HBM.
__global__ __launch_bounds__(256, 3) void fused_kernel(
    const int* __restrict__ users, const int* __restrict__ hist,
    const float* __restrict__ user_emb, const float* __restrict__ item_emb,
    const float* __restrict__ Hw,
    int n_users, int n_items, int batch, int histL,
    int NA, int NP, int NC, int ND,
    float* __restrict__ partA, float* __restrict__ partB,
    float* __restrict__ p1, float* __restrict__ p2, float* __restrict__ pss) {
    __shared__ float lds[3][64][64];   // 48 KB (3 blocks/CU)
    const int bid = blockIdx.x;
    const int t = threadIdx.x;
    if (bid < NA) {
        gram_role<false>(item_emb, nullptr, n_items, (n_items + 63) >> 6, NA, bid,
                         partA, lds, t);
    } else if (bid < NA + NP) {
        pos_role(users, hist, user_emb, item_emb, Hw, batch, histL,
                 bid - NA, NP, p1, p2, lds, t);
    } else if (bid < NA + NP + NC) {
        sumsq_role(user_emb, n_users * 16, bid - NA - NP, NC, pss, lds, t);
    } else {
        gram_role<true>(user_emb, users, batch, (batch + 63) >> 6, ND,
                        bid - NA - NP - NC, partB, lds, t);
    }
}

__global__ __launch_bounds__(256) void reduce_gram_kernel(
    const float* __restrict__ pa, int na, float* __restrict__ GI,
    const float* __restrict__ pb, int nb, float* __restrict__ GU) {
    const int e = blockIdx.x * 256 + threadIdx.x;   // grid 24 -> 6144
    const float* p; float* dst; int n, ee;
    if (e < 3072)      { p = pa; dst = GI; n = na; ee = e; }
    else if (e < 6144) { p = pb; dst = GU; n = nb; ee = e - 3072; }
    else return;
    float s[8] = {0.f,0.f,0.f,0.f,0.f,0.f,0.f,0.f};
    int b = 0;
    for (; b + 8 <= n; b += 8)
#pragma unroll
        for (int u = 0; u < 8; ++u) s[u] += p[(size_t)(b + u) * 3072 + ee];
    for (; b < n; ++b) s[0] += p[(size_t)b * 3072 + ee];
    dst[ee] = ((s[0]+s[1])+(s[2]+s[3])) + ((s[4]+s[5])+(s[6]+s[7]));
}

__global__ __launch_bounds__(256) void finalize_kernel(
    const float* __restrict__ GI, const float* __restrict__ GU,
    const float* __restrict__ Hw,
    const float* __restrict__ p1, const float* __restrict__ p2, int npos,
    const float* __restrict__ ssq, int nss, float* __restrict__ outp) {
    const int t = threadIdx.x;
    float tsum = 0.f, trace = 0.f, s1 = 0.f, s2 = 0.f, su = 0.f;
    for (int e = t; e < 3072; e += 256) {
        const int tile = e >> 10, r = (e & 1023) >> 5, cc = e & 31;
        const int i = (tile == 2) ? r + 32 : r;
        const int j = (tile == 0) ? cc : cc + 32;
        const float w = (tile == 1) ? 2.0f : 1.0f;
        const float gi = GI[e];
        tsum += w * gi * GU[e] * Hw[i] * Hw[j];
        if (i == j) trace += gi;
    }
    for (int e = t; e < npos; e += 256) { s1 += p1[e]; s2 += p2[e]; }
    for (int e = t; e < nss; e += 256) su += ssq[e];
#pragma unroll
    for (int off = 32; off >= 1; off >>= 1) {
        tsum += __shfl_xor(tsum, off, 64);
        trace += __shfl_xor(trace, off, 64);
        s1 += __shfl_xor(s1, off, 64);
        s2 += __shfl_xor(s2, off, 64);
        su += __shfl_xor(su, off, 64);
    }
    __shared__ float rr[4][5];
    if ((t & 63) == 0) {
        rr[t >> 6][0] = tsum; rr[t >> 6][1] = trace; rr[t >> 6][2] = s1;
        rr[t >> 6][3] = s2;   rr[t >> 6][4] = su;
    }
    __syncthreads();
    if (t == 0) {
        const float tt = rr[0][0] + rr[1][0] + rr[2][0] + rr[3][0];
        const float tr = rr[0][1] + rr[1][1] + rr[2][1] + rr[3][1];
        const float a1 = rr[0][2] + rr[1][2] + rr[2][2] + rr[3][2];
        const float a2 = rr[0][3] + rr[1][3] + rr[2][3] + rr[3][3];
        const float au = rr[0][4] + rr[1][4] + rr[2][4] + rr[3][4];
        const float reg = 1e-4f * (sqrtf(au) + sqrtf(tr));
        const float loss = 0.5f * tt + 0.5f * a2 - 2.0f * a1 + reg;
        outp[0] = loss; outp[1] = reg; outp[2] = reg;
    }
}

extern "C" void kernel_launch(void* const* d_in, const int* in_sizes, int n_in,
                              void* d_out, int out_size, void* d_ws, size_t ws_size,
                              hipStream_t stream) {
    const int*   users    = (const int*)d_in[0];
    const int*   hist     = (const int*)d_in[1];
    const float* user_emb = (const float*)d_in[2];
    const float* item_emb = (const float*)d_in[3];
    const float* Hw       = (const float*)d_in[4];
    float* outp = (float*)d_out;
    float* ws   = (float*)d_ws;

    const int n_users = in_sizes[2] / 64;            // 200000
    const int n_items = in_sizes[3] / 64;            // 1000000
    const int batch   = in_sizes[0];                 // 4096
    const int histL   = in_sizes[1] / n_users;       // 200

    // role partition (sum = 1024); gram overweighted (suspected straggler)
    int NA = 560, NP = 392, NC = 64, ND = 8;
    // ws layout (floats)
    const size_t o_gi = 0, o_gu = 3072, o_p1 = 6144, o_p2 = 7168, o_ss = 8192;
    const size_t o_part = 8704;
    long availf = (long)(ws_size / 4) - (long)o_part - (long)ND * 3072;
    if ((long)NA * 3072 > availf) {                  // shrink if ws is tight
        NA = (int)(availf / 3072);
        if (NA < 8) NA = 8;
    }
    float* partA = ws + o_part;
    float* partB = partA + (size_t)NA * 3072;

    fused_kernel<<<NA + NP + NC + ND, 256, 0, stream>>>(
        users, hist, user_emb, item_emb, Hw,
        n_users, n_items, batch, histL,
        NA, NP, NC, ND,
        partA, partB, ws + o_p1, ws + o_p2, ws + o_ss);
    reduce_gram_kernel<<<24, 256, 0, stream>>>(partA, NA, ws + o_gi,
                                               partB, ND, ws + o_gu);
    finalize_kernel<<<1, 256, 0, stream>>>(ws + o_gi, ws + o_gu, Hw,
                                           ws + o_p1, ws + o_p2, NP,
                                           ws + o_ss, NC, outp);
}

// Round 6
// 161.720 us; speedup vs baseline: 1.0951x; 1.0951x over previous
//
#include <hip/hip_runtime.h>
#include <hip/hip_bf16.h>

typedef __bf16 bf16x8 __attribute__((ext_vector_type(8)));
typedef float f32x16 __attribute__((ext_vector_type(16)));

// ---- Gram of [nrows x 64] (optional gather) via bf16 MFMA, LDS-free --------
// Each wave owns disjoint 16-row K-chunks. Lane (c, kh) reads col c / c+32 of
// rows kb..kb+7 directly into registers (the exact 32x32x16 A/B fragment
// pattern, verified R2). Explicit register prefetch of the next chunk's 16
// loads keeps one full chunk in flight per wave at all times.
template<bool GATHER>
__global__ __launch_bounds__(256) void gram_kernel(
    const float* __restrict__ emb, const int* __restrict__ idx,
    int nrows, int nwaves_total, float* __restrict__ partial) {
    const int t = threadIdx.x, lane = t & 63, wave = t >> 6;
    const int c = lane & 31, kh = lane >> 5;
    const int wid = blockIdx.x * 4 + wave;
    const int step = nwaves_total * 16;

    f32x16 g00 = {}, g01 = {}, g11 = {};
    float cur0[8], cur1[8];

    int k0 = wid * 16;
    if (k0 < nrows) {
        const int kb = k0 + kh * 8;
#pragma unroll
        for (int j = 0; j < 8; ++j) {
            const size_t rb = (GATHER ? (size_t)idx[kb + j] : (size_t)(kb + j)) * 64;
            cur0[j] = emb[rb + c];
            cur1[j] = emb[rb + 32 + c];
        }
    }
    for (; k0 < nrows; k0 += step) {
        float nx0[8], nx1[8];
        const int k1 = k0 + step;
        if (k1 < nrows) {                       // prefetch next chunk
            const int kb = k1 + kh * 8;
#pragma unroll
            for (int j = 0; j < 8; ++j) {
                const size_t rb = (GATHER ? (size_t)idx[kb + j] : (size_t)(kb + j)) * 64;
                nx0[j] = emb[rb + c];
                nx1[j] = emb[rb + 32 + c];
            }
        } else {
#pragma unroll
            for (int j = 0; j < 8; ++j) { nx0[j] = 0.f; nx1[j] = 0.f; }
        }
        bf16x8 f0, f1;                          // nrows % 16 == 0 in this problem
#pragma unroll
        for (int j = 0; j < 8; ++j) {
            f0[j] = (__bf16)cur0[j];
            f1[j] = (__bf16)cur1[j];
        }
        g00 = __builtin_amdgcn_mfma_f32_32x32x16_bf16(f0, f0, g00, 0, 0, 0);
        g01 = __builtin_amdgcn_mfma_f32_32x32x16_bf16(f0, f1, g01, 0, 0, 0);
        g11 = __builtin_amdgcn_mfma_f32_32x32x16_bf16(f1, f1, g11, 0, 0, 0);
#pragma unroll
        for (int j = 0; j < 8; ++j) { cur0[j] = nx0[j]; cur1[j] = nx1[j]; }
    }

    // block reduce (4 waves) in LDS, plain per-block partial, no atomics
    __shared__ float red[3072];
    __syncthreads();
    for (int w = 0; w < 4; ++w) {
        if (wave == w) {
#pragma unroll
            for (int r = 0; r < 16; ++r) {
                const int cell = ((r & 3) + 8 * (r >> 2) + 4 * kh) * 32 + c;
                if (w == 0) {
                    red[cell] = g00[r]; red[1024 + cell] = g01[r]; red[2048 + cell] = g11[r];
                } else {
                    red[cell] += g00[r]; red[1024 + cell] += g01[r]; red[2048 + cell] += g11[r];
                }
            }
        }
        __syncthreads();
    }
    float* outp = partial + (size_t)blockIdx.x * 3072;
    for (int i = t; i < 3072; i += 256) outp[i] = red[i];
}

// ---- pos: one wave per batch element, no block sync, ILP-4 gathers ---------
__global__ __launch_bounds__(256) void pos_kernel(
    const int* __restrict__ users, const int* __restrict__ hist,
    const float* __restrict__ user_emb, const float* __restrict__ item_emb,
    const float* __restrict__ Hw, int batch, int histL,
    float* __restrict__ p1, float* __restrict__ p2) {
    const int t = threadIdx.x, lane = t & 63, wave = t >> 6;
    const int w = blockIdx.x * 4 + wave;        // wave id == batch index
    if (w >= batch) return;
    const int iu = users[w];
    const int k = lane & 15, g = lane >> 4;
    const float4 vu = *reinterpret_cast<const float4*>(user_emb + (size_t)iu * 64 + k * 4);
    const float4 vh = *reinterpret_cast<const float4*>(Hw + k * 4);
    const float4 uh = make_float4(vu.x * vh.x, vu.y * vh.y, vu.z * vh.z, vu.w * vh.w);
    const int* hrow = hist + (size_t)iu * histL;

    float s1 = 0.f, s2 = 0.f;
    int l = g;
    for (; l + 12 < histL; l += 16) {           // 4 groups x ILP-4 -> stride 16
        int it[4];
#pragma unroll
        for (int u = 0; u < 4; ++u) it[u] = hrow[l + 4 * u];
        float d[4];
#pragma unroll
        for (int u = 0; u < 4; ++u) {
            const float4 v = *reinterpret_cast<const float4*>(
                item_emb + (size_t)it[u] * 64 + k * 4);
            d[u] = v.x * uh.x + v.y * uh.y + v.z * uh.z + v.w * uh.w;
        }
#pragma unroll
        for (int u = 0; u < 4; ++u) {
            float dd = d[u];
            dd += __shfl_xor(dd, 1, 16);
            dd += __shfl_xor(dd, 2, 16);
            dd += __shfl_xor(dd, 4, 16);
            dd += __shfl_xor(dd, 8, 16);
            s1 += dd;                            // replicated x16; scaled at end
            s2 = fmaf(dd, dd, s2);
        }
    }
    for (; l < histL; l += 4) {
        const int it = hrow[l];
        const float4 v = *reinterpret_cast<const float4*>(
            item_emb + (size_t)it * 64 + k * 4);
        float dd = v.x * uh.x + v.y * uh.y + v.z * uh.z + v.w * uh.w;
        dd += __shfl_xor(dd, 1, 16);
        dd += __shfl_xor(dd, 2, 16);
        dd += __shfl_xor(dd, 4, 16);
        dd += __shfl_xor(dd, 8, 16);
        s1 += dd;
        s2 = fmaf(dd, dd, s2);
    }
    s1 += __shfl_xor(s1, 16, 64); s1 += __shfl_xor(s1, 32, 64);
    s2 += __shfl_xor(s2, 16, 64); s2 += __shfl_xor(s2, 32, 64);
    if (lane == 0) { p1[w] = s1 * 0.0625f; p2[w] = s2 * 0.0625f; }
}

// ---- sumsq of flat f32 buffer ----------------------------------------------
__global__ __launch_bounds__(256) void sumsq_kernel(
    const float* __restrict__ x, int n4, float* __restrict__ part) {
    float s = 0.f;
    for (int i = blockIdx.x * 256 + threadIdx.x; i < n4; i += gridDim.x * 256) {
        const float4 v = reinterpret_cast<const float4*>(x)[i];
        s = fmaf(v.x, v.x, s); s = fmaf(v.y, v.y, s);
        s = fmaf(v.z, v.z, s); s = fmaf(v.w, v.w, s);
    }
#pragma unroll
    for (int off = 32; off >= 1; off >>= 1) s += __shfl_xor(s, off, 64);
    __shared__ float r[4];
    if ((threadIdx.x & 63) == 0) r[threadIdx.x >> 6] = s;
    __syncthreads();
    if (threadIdx.x == 0) part[blockIdx.x] = r[0] + r[1] + r[2] + r[3];
}

__global__ __launch_bounds__(256) void reduce_gram_kernel(
    const float* __restrict__ pa, int na, float* __restrict__ GI,
    const float* __restrict__ pb, int nb, float* __restrict__ GU) {
    const int e = blockIdx.x * 256 + threadIdx.x;   // grid 24 -> 6144
    const float* p; float* dst; int n, ee;
    if (e < 3072)      { p = pa; dst = GI; n = na; ee = e; }
    else if (e < 6144) { p = pb; dst = GU; n = nb; ee = e - 3072; }
    else return;
    float s[8] = {0.f,0.f,0.f,0.f,0.f,0.f,0.f,0.f};
    int b = 0;
    for (; b + 8 <= n; b += 8)
#pragma unroll
        for (int u = 0; u < 8; ++u) s[u] += p[(size_t)(b + u) * 3072 + ee];
    for (; b < n; ++b) s[0] += p[(size_t)b * 3072 + ee];
    dst[ee] = ((s[0]+s[1])+(s[2]+s[3])) + ((s[4]+s[5])+(s[6]+s[7]));
}

__global__ __launch_bounds__(256) void finalize_kernel(
    const float* __restrict__ GI, const float* __restrict__ GU,
    const float* __restrict__ Hw,
    const float* __restrict__ p1, const float* __restrict__ p2, int npos,
    const float* __restrict__ ssq, int nss, float* __restrict__ outp) {
    const int t = threadIdx.x;
    float tsum = 0.f, trace = 0.f, s1 = 0.f, s2 = 0.f, su = 0.f;
    for (int e = t; e < 3072; e += 256) {
        const int tile = e >> 10, r = (e & 1023) >> 5, cc = e & 31;
        const int i = (tile == 2) ? r + 32 : r;
        const int j = (tile == 0) ? cc : cc + 32;
        const float w = (tile == 1) ? 2.0f : 1.0f;
        const float gi = GI[e];
        tsum += w * gi * GU[e] * Hw[i] * Hw[j];
        if (i == j) trace += gi;
    }
    for (int e = t; e < npos; e += 256) { s1 += p1[e]; s2 += p2[e]; }
    for (int e = t; e < nss; e += 256) su += ssq[e];
#pragma unroll
    for (int off = 32; off >= 1; off >>= 1) {
        tsum += __shfl_xor(tsum, off, 64);
        trace += __shfl_xor(trace, off, 64);
        s1 += __shfl_xor(s1, off, 64);
        s2 += __shfl_xor(s2, off, 64);
        su += __shfl_xor(su, off, 64);
    }
    __shared__ float rr[4][5];
    if ((t & 63) == 0) {
        rr[t >> 6][0] = tsum; rr[t >> 6][1] = trace; rr[t >> 6][2] = s1;
        rr[t >> 6][3] = s2;   rr[t >> 6][4] = su;
    }
    __syncthreads();
    if (t == 0) {
        const float tt = rr[0][0] + rr[1][0] + rr[2][0] + rr[3][0];
        const float tr = rr[0][1] + rr[1][1] + rr[2][1] + rr[3][1];
        const float a1 = rr[0][2] + rr[1][2] + rr[2][2] + rr[3][2];
        const float a2 = rr[0][3] + rr[1][3] + rr[2][3] + rr[3][3];
        const float au = rr[0][4] + rr[1][4] + rr[2][4] + rr[3][4];
        const float reg = 1e-4f * (sqrtf(au) + sqrtf(tr));
        const float loss = 0.5f * tt + 0.5f * a2 - 2.0f * a1 + reg;
        outp[0] = loss; outp[1] = reg; outp[2] = reg;
    }
}

extern "C" void kernel_launch(void* const* d_in, const int* in_sizes, int n_in,
                              void* d_out, int out_size, void* d_ws, size_t ws_size,
                              hipStream_t stream) {
    const int*   users    = (const int*)d_in[0];
    const int*   hist     = (const int*)d_in[1];
    const float* user_emb = (const float*)d_in[2];
    const float* item_emb = (const float*)d_in[3];
    const float* Hw       = (const float*)d_in[4];
    float* outp = (float*)d_out;
    float* ws   = (float*)d_ws;

    const int n_users = in_sizes[2] / 64;            // 200000
    const int n_items = in_sizes[3] / 64;            // 1000000
    const int batch   = in_sizes[0];                 // 4096
    const int histL   = in_sizes[1] / n_users;       // 200

    int NB_ITEM = 1024;                              // 4096 waves, all resident
    const int NB_USER = 64;                          // 256 waves, 1 chunk each
    const int NSS = 2048;

    // ws layout (floats)
    const size_t o_gi = 0, o_gu = 3072, o_p1 = 6144;
    const size_t o_p2 = o_p1 + (size_t)batch;
    const size_t o_ss = o_p2 + (size_t)batch;
    const size_t o_part = o_ss + NSS;
    long availf = (long)(ws_size / 4) - (long)o_part - (long)NB_USER * 3072;
    if ((long)NB_ITEM * 3072 > availf) {
        NB_ITEM = (int)(availf / 3072);
        if (NB_ITEM < 8) NB_ITEM = 8;
    }
    float* partA = ws + o_part;
    float* partB = partA + (size_t)NB_ITEM * 3072;

    gram_kernel<false><<<NB_ITEM, 256, 0, stream>>>(
        item_emb, nullptr, n_items, NB_ITEM * 4, partA);
    pos_kernel<<<(batch + 3) / 4, 256, 0, stream>>>(
        users, hist, user_emb, item_emb, Hw, batch, histL,
        ws + o_p1, ws + o_p2);
    gram_kernel<true><<<NB_USER, 256, 0, stream>>>(
        user_emb, users, batch, NB_USER * 4, partB);
    sumsq_kernel<<<NSS, 256, 0, stream>>>(user_emb, in_sizes[2] / 4, ws + o_ss);
    reduce_gram_kernel<<<24, 256, 0, stream>>>(partA, NB_ITEM, ws + o_gi,
                                               partB, NB_USER, ws + o_gu);
    finalize_kernel<<<1, 256, 0, stream>>>(ws + o_gi, ws + o_gu, Hw,
                                           ws + o_p1, ws + o_p2, batch,
                                           ws + o_ss, NSS, outp);
}